// Round 16
// baseline (98.187 us; speedup 1.0000x reference)
//
#include <hip/hip_runtime.h>

#define B_N 4096
#define M_N 3
#define D_N 256
#define LOG2E 1.44269504088896340736f
#define LN2   0.69314718055994530942f
#define C_OFF   64.0f
#define T_CLAMP 112.0f

typedef __bf16 bf16x8 __attribute__((ext_vector_type(8)));
typedef float  f32x4  __attribute__((ext_vector_type(4)));

__device__ __forceinline__ unsigned short f2bf(float f) {
    unsigned int u = __float_as_uint(f);
    u += 0x7FFFu + ((u >> 16) & 1u);   // round-to-nearest-even
    return (unsigned short)(u >> 16);
}
__device__ __forceinline__ float bf2f(unsigned short h) {
    return __uint_as_float(((unsigned int)h) << 16);
}

// tokens [i][m][d] f32 -> tokb [m][i][d] bf16; norm2[m*B+i] = sum(bf16(x)^2)
__global__ void cvt_kernel(const float* __restrict__ in, unsigned short* __restrict__ out,
                           float* __restrict__ norm2) {
    int idx = blockIdx.x * blockDim.x + threadIdx.x;   // 786432 float4s
    float4 v = reinterpret_cast<const float4*>(in)[idx];
    int i   = idx / 192;            // 192 = M*D/4
    int rem = idx - i * 192;
    int m   = rem >> 6;
    int d4  = rem & 63;
    ushort4 o;
    o.x = f2bf(v.x); o.y = f2bf(v.y); o.z = f2bf(v.z); o.w = f2bf(v.w);
    reinterpret_cast<ushort4*>(out)[((size_t)m * B_N + i) * 64 + d4] = o;
    float nx = bf2f(o.x), ny = bf2f(o.y), nz = bf2f(o.z), nw = bf2f(o.w);
    float s = nx * nx + ny * ny + nz * nz + nw * nw;
#pragma unroll
    for (int msk = 1; msk < 64; msk <<= 1) s += __shfl_xor(s, msk);
    if ((threadIdx.x & 63) == 0) norm2[m * B_N + i] = s;  // wave spans one (i,m) row
}

// Symmetric-pair main, NO ATOMICS. Block = panel pair (a<=b), panels of 256
// rows. Tile = X_a . X_b^T (256x256, K=256): 16 phases x 16 cols, dbuf LDS,
// verified XOR swizzle; 4 waves x 64 rows (rt=4, r10-measured no-spill form).
// Each element feeds row-side (panel a) and, for a<b, col-side (panel b).
// Slot partition (zero collisions): sample i in panel p gets row-side of
// block (p,b) in slot b, col-side of block (a,p),a<p in slot a -> 16 slots.
// Partials stored bf16 (ushort2) -> 786 KB, plain stores only.
// grid = 3m x 136 pairs = 408 blocks, all co-resident at 2/CU.
__global__ __launch_bounds__(256, 2) void main_kernel(
    const unsigned short* __restrict__ tokb, const int* __restrict__ labels,
    unsigned short* __restrict__ partials) {
    int raw = blockIdx.x;
    int bid = (raw & 7) * 51 + (raw >> 3);   // bijective XCD swizzle (408 = 8*51)
    int m    = bid / 136;
    int beta = bid - m * 136;
    int b = 0;                                // triangular decode
    while ((b + 1) * (b + 2) / 2 <= beta) ++b;
    int a = beta - (b * (b + 1)) / 2;         // 0 <= a <= b <= 15
    bool offd = (a != b);
    int cb = b * 256;

    int tid  = threadIdx.x;
    int wave = tid >> 6, lane = tid & 63;
    int lr = lane & 15, lk = lane >> 4;
    const unsigned short* tm = tokb + (size_t)m * (B_N * D_N);

    __shared__ __align__(16) char ldsB[2][8192];
    __shared__ int labl[256];
    __shared__ float colbuf[4][16][16][2];
    labl[tid] = labels[cb + tid];

    // A fragments: rows r0 + rt*16 + lr (panel a), registers for whole kernel
    int r0 = a * 256 + wave * 64;
    bf16x8 afrag[4][8];
#pragma unroll
    for (int rt = 0; rt < 4; ++rt) {
        const unsigned short* rp = tm + (size_t)(r0 + rt * 16 + lr) * D_N + lk * 8;
#pragma unroll
        for (int kf = 0; kf < 8; ++kf)
            afrag[rt][kf] = *reinterpret_cast<const bf16x8*>(rp + kf * 32);
    }
    int labr[4][4];
#pragma unroll
    for (int rt = 0; rt < 4; ++rt)
#pragma unroll
        for (int j = 0; j < 4; ++j)
            labr[rt][j] = labels[r0 + rt * 16 + lk * 4 + j];

    float S[4][4], P[4][4];
#pragma unroll
    for (int rt = 0; rt < 4; ++rt)
#pragma unroll
        for (int j = 0; j < 4; ++j) { S[rt][j] = 0.f; P[rt][j] = 0.f; }

    // Staging map (involution verified r4-r15; cb%8==0): LDS[cit][ch] =
    // G[cb+kb*16+cit][ch ^ (cit&7)]; ds_read applies the same XOR.
    int lc  = tid >> 5;
    int w   = tid & 31;
    int sch = w ^ (lc & 7);
    const unsigned short* sbase = tm + (size_t)(cb + lc) * D_N + sch * 8;

    // prologue: tile 0 -> buf0
    {
        bf16x8 t0 = *reinterpret_cast<const bf16x8*>(sbase);
        bf16x8 t1 = *reinterpret_cast<const bf16x8*>(sbase + 8 * D_N);
        *reinterpret_cast<bf16x8*>(&ldsB[0][tid * 16])        = t0;
        *reinterpret_cast<bf16x8*>(&ldsB[0][4096 + tid * 16]) = t1;
    }

    for (int kb = 0; kb < 16; ++kb) {
        int cur = kb & 1;
        __syncthreads();   // buf[cur] staged; prior reads of buf[cur^1] drained

        int nkb = (kb + 1) & 15;   // wrap: last-iter load/write dead but safe
        const unsigned short* np = sbase + (size_t)nkb * (16 * D_N);
        bf16x8 nt0 = *reinterpret_cast<const bf16x8*>(np);
        bf16x8 nt1 = *reinterpret_cast<const bf16x8*>(np + 8 * D_N);

        const char* bp = ldsB[cur];
        int swz = (lr & 7) << 4;
        bf16x8 bfrag[8];
#pragma unroll
        for (int kf = 0; kf < 8; ++kf)
            bfrag[kf] = *reinterpret_cast<const bf16x8*>(
                bp + lr * 512 + (((kf * 4 + lk) << 4) ^ swz));
        int labc = labl[kb * 16 + lr];

        f32x4 acc[4];
#pragma unroll
        for (int rt = 0; rt < 4; ++rt) acc[rt] = f32x4{0.f, 0.f, 0.f, 0.f};
#pragma unroll
        for (int kf = 0; kf < 8; ++kf) {
#pragma unroll
            for (int rt = 0; rt < 4; ++rt)
                acc[rt] = __builtin_amdgcn_mfma_f32_16x16x32_bf16(
                    afrag[rt][kf], bfrag[kf], acc[rt], 0, 0, 0);
        }

        float cs = 0.f, cp = 0.f;
        int cg0 = cb + kb * 16;
        if ((cg0 < r0 + 64) && (cg0 + 16 > r0)) {   // only in diag blocks
            int colg = cg0 + lr;
#pragma unroll
            for (int rt = 0; rt < 4; ++rt) {
#pragma unroll
                for (int j = 0; j < 4; ++j) {
                    float s2 = acc[rt][j];
                    float t = fminf(fmaf(s2, LOG2E, -C_OFF), T_CLAMP);
                    float e = __builtin_amdgcn_exp2f(t);
                    int row = r0 + rt * 16 + lk * 4 + j;
                    e = (colg == row) ? 0.f : e;    // exclude self from partition
                    bool mt = (labc == labr[rt][j]);
                    S[rt][j] += e;  P[rt][j] += mt ? s2 : 0.f;
                    cs += e;        cp += mt ? s2 : 0.f;
                }
            }
        } else {
#pragma unroll
            for (int rt = 0; rt < 4; ++rt) {
#pragma unroll
                for (int j = 0; j < 4; ++j) {
                    float s2 = acc[rt][j];
                    float t = fminf(fmaf(s2, LOG2E, -C_OFF), T_CLAMP);
                    float e = __builtin_amdgcn_exp2f(t);
                    bool mt = (labc == labr[rt][j]);
                    S[rt][j] += e;  P[rt][j] += mt ? s2 : 0.f;
                    cs += e;        cp += mt ? s2 : 0.f;
                }
            }
        }

        // col-side: sum over the wave's 64 rows (4 lanes share column lr)
        cs += __shfl_xor(cs, 16); cs += __shfl_xor(cs, 32);
        cp += __shfl_xor(cp, 16); cp += __shfl_xor(cp, 32);
        if (lk == 0) { colbuf[wave][kb][lr][0] = cs; colbuf[wave][kb][lr][1] = cp; }

        // write next tile (other buffer); barrier at loop top publishes it
        char* dst = (char*)ldsB[cur ^ 1];
        *reinterpret_cast<bf16x8*>(dst + tid * 16)        = nt0;
        *reinterpret_cast<bf16x8*>(dst + 4096 + tid * 16) = nt1;
    }

    __syncthreads();   // colbuf complete

    // row-side flush: reduce over 16 col-lanes, plain store to slot b
#pragma unroll
    for (int rt = 0; rt < 4; ++rt)
#pragma unroll
        for (int j = 0; j < 4; ++j) {
            float sv = S[rt][j], pv = P[rt][j];
#pragma unroll
            for (int msk = 1; msk < 16; msk <<= 1) {
                sv += __shfl_xor(sv, msk);
                pv += __shfl_xor(pv, msk);
            }
            if (lr == 0) {
                int row = r0 + rt * 16 + lk * 4 + j;
                ushort2 q; q.x = f2bf(sv); q.y = f2bf(pv);
                *reinterpret_cast<ushort2*>(
                    partials + ((size_t)(m * B_N + row) * 16 + b) * 2) = q;
            }
        }

    // col-side flush (off-diag only): sum colbuf over 4 waves, store to slot a
    if (offd) {
        int kb = tid >> 4, cr = tid & 15;
        float sv = colbuf[0][kb][cr][0] + colbuf[1][kb][cr][0]
                 + colbuf[2][kb][cr][0] + colbuf[3][kb][cr][0];
        float pv = colbuf[0][kb][cr][1] + colbuf[1][kb][cr][1]
                 + colbuf[2][kb][cr][1] + colbuf[3][kb][cr][1];
        int col = cb + tid;
        ushort2 q; q.x = f2bf(sv); q.y = f2bf(pv);
        *reinterpret_cast<ushort2*>(
            partials + ((size_t)(m * B_N + col) * 16 + a) * 2) = q;
    }
}

// one thread per (m,i): merge 16 bf16 slot-partials, finish the loss term.
__global__ void reduce_kernel(const unsigned short* __restrict__ partials,
                              const float* __restrict__ norm2,
                              const int* __restrict__ labels,
                              float* __restrict__ blockpart,
                              int* __restrict__ nvout) {
    __shared__ int h[32];
    int tid = threadIdx.x;
    if (tid < 32) h[tid] = 0;
    __syncthreads();
    for (int i = tid; i < B_N; i += 256) atomicAdd(&h[labels[i]], 1);
    __syncthreads();
    if (blockIdx.x == 0 && tid == 0) {
        int nv = 0;
#pragma unroll
        for (int c = 0; c < 32; ++c) nv += (h[c] >= 2) ? h[c] : 0;
        nvout[0] = nv;
    }
    int gid = blockIdx.x * 256 + tid;   // 12288 = m*4096 + i
    int i = gid & 4095;
    const ushort2* pp = reinterpret_cast<const ushort2*>(partials + (size_t)gid * 32);
    float S = 0.f, P = 0.f;
#pragma unroll
    for (int s = 0; s < 16; ++s) {
        ushort2 q = pp[s];
        S += bf2f(q.x); P += bf2f(q.y);
    }
    P -= norm2[gid];                       // remove self-sim from positive sum
    int pc = h[labels[i]] - 1;
    float contrib = (pc > 0)
        ? (__builtin_amdgcn_logf(S) + C_OFF) * LN2 - P / (float)pc
        : 0.f;
#pragma unroll
    for (int off = 32; off >= 1; off >>= 1) contrib += __shfl_down(contrib, off);
    __shared__ float w4[4];
    if ((tid & 63) == 0) w4[tid >> 6] = contrib;
    __syncthreads();
    if (tid == 0) blockpart[blockIdx.x] = w4[0] + w4[1] + w4[2] + w4[3];
}

__global__ void final_kernel(const float* __restrict__ blockpart, const int* __restrict__ nv,
                             float* __restrict__ out) {
    int lane = threadIdx.x;
    float s = (lane < 48) ? blockpart[lane] : 0.f;
#pragma unroll
    for (int off = 32; off >= 1; off >>= 1) s += __shfl_down(s, off);
    if (lane == 0) out[0] = s / (float)(nv[0] * M_N);
}

extern "C" void kernel_launch(void* const* d_in, const int* in_sizes, int n_in,
                              void* d_out, int out_size, void* d_ws, size_t ws_size,
                              hipStream_t stream) {
    const float* tokens = (const float*)d_in[0];
    const int*   labels = (const int*)d_in[1];
    float* out = (float*)d_out;

    char* ws = (char*)d_ws;
    int*    nv        = (int*)(ws + 128);                   // 1 int
    float*  blockpart = (float*)(ws + 256);                 // 48 floats
    float*  norm2     = (float*)(ws + 1024);                // 12288 f32, ends 50176
    unsigned short* partials = (unsigned short*)(ws + 65536); // 12288*16*4B = 786432 B
    unsigned short* tokb = (unsigned short*)(ws + 1048576); // 6.29 MB (ends 7.34 MB)

    cvt_kernel<<<3072, 256, 0, stream>>>(tokens, tokb, norm2);
    main_kernel<<<408, 256, 0, stream>>>(tokb, labels, partials);
    reduce_kernel<<<48, 256, 0, stream>>>(partials, norm2, labels, blockpart, nv);
    final_kernel<<<1, 64, 0, stream>>>(blockpart, nv, out);
}

// Round 17
// 97.097 us; speedup vs baseline: 1.0112x; 1.0112x over previous
//
#include <hip/hip_runtime.h>

#define B_N 4096
#define M_N 3
#define D_N 256
#define LOG2E 1.44269504088896340736f
#define LN2   0.69314718055994530942f
#define C_OFF   64.0f
#define T_CLAMP 112.0f

typedef __bf16 bf16x8 __attribute__((ext_vector_type(8)));
typedef float  f32x4  __attribute__((ext_vector_type(4)));

__device__ __forceinline__ unsigned short f2bf(float f) {
    unsigned int u = __float_as_uint(f);
    u += 0x7FFFu + ((u >> 16) & 1u);   // round-to-nearest-even
    return (unsigned short)(u >> 16);
}
__device__ __forceinline__ float bf2f(unsigned short h) {
    return __uint_as_float(((unsigned int)h) << 16);
}

// tokens [i][m][d] f32 -> tokb [m][i][d] bf16; norm2[m*B+i] = sum(bf16(x)^2)
__global__ void cvt_kernel(const float* __restrict__ in, unsigned short* __restrict__ out,
                           float* __restrict__ norm2) {
    int idx = blockIdx.x * blockDim.x + threadIdx.x;   // 786432 float4s
    float4 v = reinterpret_cast<const float4*>(in)[idx];
    int i   = idx / 192;            // 192 = M*D/4
    int rem = idx - i * 192;
    int m   = rem >> 6;
    int d4  = rem & 63;
    ushort4 o;
    o.x = f2bf(v.x); o.y = f2bf(v.y); o.z = f2bf(v.z); o.w = f2bf(v.w);
    reinterpret_cast<ushort4*>(out)[((size_t)m * B_N + i) * 64 + d4] = o;
    float nx = bf2f(o.x), ny = bf2f(o.y), nz = bf2f(o.z), nw = bf2f(o.w);
    float s = nx * nx + ny * ny + nz * nz + nw * nw;
#pragma unroll
    for (int msk = 1; msk < 64; msk <<= 1) s += __shfl_xor(s, msk);
    if ((threadIdx.x & 63) == 0) norm2[m * B_N + i] = s;  // wave spans one (i,m) row
}

// Symmetric-pair main, no atomics, 512 threads = 8 waves x 32 rows.
// Block = panel pair (a<=b), panels of 256 rows; tile X_a.X_b^T (256x256,K=256),
// 16 phases x 16 cols, dbuf LDS + verified XOR swizzle. Per-wave per-phase work
// is bit-identical to the r4/r13 measured form (rt=2). Row-side -> slot b,
// col-side (a<b) -> slot a; partials [slot][m][row] bf16 pairs so each block
// flush is two 1KB contiguous regions (coalesced, no write-allocate blowup).
// grid = 3m x 136 pairs = 408 blocks, 2 blocks/CU co-resident (~3.2 w/SIMD).
__global__ __launch_bounds__(512, 4) void main_kernel(
    const unsigned short* __restrict__ tokb, const int* __restrict__ labels,
    ushort2* __restrict__ partials) {
    int raw = blockIdx.x;
    int bid = (raw & 7) * 51 + (raw >> 3);   // bijective XCD swizzle (408 = 8*51)
    int m    = bid / 136;
    int beta = bid - m * 136;
    int b = 0;                                // triangular decode
    while ((b + 1) * (b + 2) / 2 <= beta) ++b;
    int a = beta - (b * (b + 1)) / 2;         // 0 <= a <= b <= 15
    bool offd = (a != b);
    int cb = b * 256;

    int tid  = threadIdx.x;
    int wave = tid >> 6, lane = tid & 63;
    int lr = lane & 15, lk = lane >> 4;
    const unsigned short* tm = tokb + (size_t)m * (B_N * D_N);

    __shared__ __align__(16) char ldsB[2][8192];
    __shared__ int labl[256];
    __shared__ float colbuf[8][16][16][2];
    if (tid < 256) labl[tid] = labels[cb + tid];

    // A fragments: rows r0 + rt*16 + lr (panel a), registers for whole kernel
    int r0 = a * 256 + wave * 32;
    bf16x8 afrag[2][8];
#pragma unroll
    for (int rt = 0; rt < 2; ++rt) {
        const unsigned short* rp = tm + (size_t)(r0 + rt * 16 + lr) * D_N + lk * 8;
#pragma unroll
        for (int kf = 0; kf < 8; ++kf)
            afrag[rt][kf] = *reinterpret_cast<const bf16x8*>(rp + kf * 32);
    }
    int labr[2][4];
#pragma unroll
    for (int rt = 0; rt < 2; ++rt)
#pragma unroll
        for (int j = 0; j < 4; ++j)
            labr[rt][j] = labels[r0 + rt * 16 + lk * 4 + j];

    float S[2][4] = {{0.f, 0.f, 0.f, 0.f}, {0.f, 0.f, 0.f, 0.f}};
    float P[2][4] = {{0.f, 0.f, 0.f, 0.f}, {0.f, 0.f, 0.f, 0.f}};

    // Staging (involution verified r4-r16; cb%8==0, 16 cols ≡ 0 mod 8):
    // thread t stages ONE 16B chunk: col lc = t>>5 (0..15), chunk ch = t&31,
    // source chunk ch ^ (lc&7), LDS linear at t*16. Read applies same XOR.
    int lc  = tid >> 5;
    int ch  = tid & 31;
    const unsigned short* sbase = tm + (size_t)(cb + lc) * D_N + (ch ^ (lc & 7)) * 8;

    // prologue: tile 0 -> buf0
    *reinterpret_cast<bf16x8*>(&ldsB[0][tid * 16]) = *reinterpret_cast<const bf16x8*>(sbase);

    for (int kb = 0; kb < 16; ++kb) {
        int cur = kb & 1;
        __syncthreads();   // buf[cur] staged; prior reads of buf[cur^1] drained

        int nkb = (kb + 1) & 15;   // wrap: last-iter load/write dead but safe
        bf16x8 nt = *reinterpret_cast<const bf16x8*>(sbase + (size_t)nkb * (16 * D_N));

        const char* bp = ldsB[cur];
        int swz = (lr & 7) << 4;
        bf16x8 bfrag[8];
#pragma unroll
        for (int kf = 0; kf < 8; ++kf)
            bfrag[kf] = *reinterpret_cast<const bf16x8*>(
                bp + lr * 512 + (((kf * 4 + lk) << 4) ^ swz));
        int labc = labl[kb * 16 + lr];

        f32x4 acc0 = {0.f, 0.f, 0.f, 0.f};
        f32x4 acc1 = {0.f, 0.f, 0.f, 0.f};
#pragma unroll
        for (int kf = 0; kf < 8; ++kf) {
            acc0 = __builtin_amdgcn_mfma_f32_16x16x32_bf16(afrag[0][kf], bfrag[kf], acc0, 0, 0, 0);
            acc1 = __builtin_amdgcn_mfma_f32_16x16x32_bf16(afrag[1][kf], bfrag[kf], acc1, 0, 0, 0);
        }

        float cs = 0.f, cp = 0.f;
        int cg0 = cb + kb * 16;
        if ((cg0 < r0 + 32) && (cg0 + 16 > r0)) {   // only in diag blocks
            int colg = cg0 + lr;
#pragma unroll
            for (int rt = 0; rt < 2; ++rt) {
                f32x4 aa = rt ? acc1 : acc0;
#pragma unroll
                for (int j = 0; j < 4; ++j) {
                    float s2 = aa[j];
                    float t = fminf(fmaf(s2, LOG2E, -C_OFF), T_CLAMP);
                    float e = __builtin_amdgcn_exp2f(t);
                    int row = r0 + rt * 16 + lk * 4 + j;
                    e = (colg == row) ? 0.f : e;    // exclude self from partition
                    bool mt = (labc == labr[rt][j]);
                    S[rt][j] += e;  P[rt][j] += mt ? s2 : 0.f;
                    cs += e;        cp += mt ? s2 : 0.f;
                }
            }
        } else {
#pragma unroll
            for (int rt = 0; rt < 2; ++rt) {
                f32x4 aa = rt ? acc1 : acc0;
#pragma unroll
                for (int j = 0; j < 4; ++j) {
                    float s2 = aa[j];
                    float t = fminf(fmaf(s2, LOG2E, -C_OFF), T_CLAMP);
                    float e = __builtin_amdgcn_exp2f(t);
                    bool mt = (labc == labr[rt][j]);
                    S[rt][j] += e;  P[rt][j] += mt ? s2 : 0.f;
                    cs += e;        cp += mt ? s2 : 0.f;
                }
            }
        }

        // col-side: sum over the wave's 32 rows (lanes lr, lr+16, lr+32, lr+48)
        cs += __shfl_xor(cs, 16); cs += __shfl_xor(cs, 32);
        cp += __shfl_xor(cp, 16); cp += __shfl_xor(cp, 32);
        if (lk == 0) { colbuf[wave][kb][lr][0] = cs; colbuf[wave][kb][lr][1] = cp; }

        // write next tile (other buffer); barrier at loop top publishes it
        *reinterpret_cast<bf16x8*>(&ldsB[cur ^ 1][tid * 16]) = nt;
    }

    __syncthreads();   // colbuf complete

    // row-side flush: reduce over 16 col-lanes, contiguous store to slot b
#pragma unroll
    for (int rt = 0; rt < 2; ++rt)
#pragma unroll
        for (int j = 0; j < 4; ++j) {
            float sv = S[rt][j], pv = P[rt][j];
#pragma unroll
            for (int msk = 1; msk < 16; msk <<= 1) {
                sv += __shfl_xor(sv, msk);
                pv += __shfl_xor(pv, msk);
            }
            if (lr == 0) {
                int row = r0 + rt * 16 + lk * 4 + j;
                ushort2 q; q.x = f2bf(sv); q.y = f2bf(pv);
                partials[(size_t)(b * 3 + m) * B_N + row] = q;
            }
        }

    // col-side flush (off-diag only): sum colbuf over 8 waves, store to slot a
    if (offd && tid < 256) {
        int kb = tid >> 4, cr = tid & 15;
        float sv = 0.f, pv = 0.f;
#pragma unroll
        for (int wv = 0; wv < 8; ++wv) {
            sv += colbuf[wv][kb][cr][0];
            pv += colbuf[wv][kb][cr][1];
        }
        int col = cb + tid;   // tid == kb*16 + cr
        ushort2 q; q.x = f2bf(sv); q.y = f2bf(pv);
        partials[(size_t)(a * 3 + m) * B_N + col] = q;
    }
}

// one thread per (m,i): merge 16 bf16 slot-partials, finish the loss term.
__global__ void reduce_kernel(const ushort2* __restrict__ partials,
                              const float* __restrict__ norm2,
                              const int* __restrict__ labels,
                              float* __restrict__ blockpart,
                              int* __restrict__ nvout) {
    __shared__ int h[32];
    int tid = threadIdx.x;
    if (tid < 32) h[tid] = 0;
    __syncthreads();
    for (int i = tid; i < B_N; i += 256) atomicAdd(&h[labels[i]], 1);
    __syncthreads();
    if (blockIdx.x == 0 && tid == 0) {
        int nv = 0;
#pragma unroll
        for (int c = 0; c < 32; ++c) nv += (h[c] >= 2) ? h[c] : 0;
        nvout[0] = nv;
    }
    int gid = blockIdx.x * 256 + tid;   // 12288 = m*4096 + i
    int m = gid >> 12, i = gid & 4095;
    float S = 0.f, P = 0.f;
#pragma unroll
    for (int s = 0; s < 16; ++s) {
        ushort2 q = partials[(size_t)(s * 3 + m) * B_N + i];
        S += bf2f(q.x); P += bf2f(q.y);
    }
    P -= norm2[gid];                       // remove self-sim from positive sum
    int pc = h[labels[i]] - 1;
    float contrib = (pc > 0)
        ? (__builtin_amdgcn_logf(S) + C_OFF) * LN2 - P / (float)pc
        : 0.f;
#pragma unroll
    for (int off = 32; off >= 1; off >>= 1) contrib += __shfl_down(contrib, off);
    __shared__ float w4[4];
    if ((tid & 63) == 0) w4[tid >> 6] = contrib;
    __syncthreads();
    if (tid == 0) blockpart[blockIdx.x] = w4[0] + w4[1] + w4[2] + w4[3];
}

__global__ void final_kernel(const float* __restrict__ blockpart, const int* __restrict__ nv,
                             float* __restrict__ out) {
    int lane = threadIdx.x;
    float s = (lane < 48) ? blockpart[lane] : 0.f;
#pragma unroll
    for (int off = 32; off >= 1; off >>= 1) s += __shfl_down(s, off);
    if (lane == 0) out[0] = s / (float)(nv[0] * M_N);
}

extern "C" void kernel_launch(void* const* d_in, const int* in_sizes, int n_in,
                              void* d_out, int out_size, void* d_ws, size_t ws_size,
                              hipStream_t stream) {
    const float* tokens = (const float*)d_in[0];
    const int*   labels = (const int*)d_in[1];
    float* out = (float*)d_out;

    char* ws = (char*)d_ws;
    int*     nv        = (int*)(ws + 128);                  // 1 int
    float*   blockpart = (float*)(ws + 256);                // 48 floats
    float*   norm2     = (float*)(ws + 1024);               // 12288 f32, ends 50176
    ushort2* partials  = (ushort2*)(ws + 65536);            // 16*3*4096*4B = 786432 B
    unsigned short* tokb = (unsigned short*)(ws + 1048576); // 6.29 MB (ends 7.34 MB)

    cvt_kernel<<<3072, 256, 0, stream>>>(tokens, tokb, norm2);
    main_kernel<<<408, 512, 0, stream>>>(tokb, labels, partials);
    reduce_kernel<<<48, 256, 0, stream>>>(partials, norm2, labels, blockpart, nv);
    final_kernel<<<1, 64, 0, stream>>>(blockpart, nv, out);
}

// Round 18
// 52.960 us; speedup vs baseline: 1.8540x; 1.8334x over previous
//
#include <hip/hip_runtime.h>

#define B_N 4096
#define M_N 3
#define D_N 256
#define LOG2E 1.44269504088896340736f
#define LN2   0.69314718055994530942f
#define C_OFF   64.0f
#define T_CLAMP 112.0f

typedef __bf16 bf16x8 __attribute__((ext_vector_type(8)));
typedef float  f32x4  __attribute__((ext_vector_type(4)));

__device__ __forceinline__ unsigned short f2bf(float f) {
    unsigned int u = __float_as_uint(f);
    u += 0x7FFFu + ((u >> 16) & 1u);   // round-to-nearest-even
    return (unsigned short)(u >> 16);
}
__device__ __forceinline__ float bf2f(unsigned short h) {
    return __uint_as_float(((unsigned int)h) << 16);
}

// tokens [i][m][d] f32 -> tokb [m][i][d] bf16; norm2[m*B+i] = sum(bf16(x)^2)
__global__ void cvt_kernel(const float* __restrict__ in, unsigned short* __restrict__ out,
                           float* __restrict__ norm2) {
    int idx = blockIdx.x * blockDim.x + threadIdx.x;   // 786432 float4s
    float4 v = reinterpret_cast<const float4*>(in)[idx];
    int i   = idx / 192;            // 192 = M*D/4
    int rem = idx - i * 192;
    int m   = rem >> 6;
    int d4  = rem & 63;
    ushort4 o;
    o.x = f2bf(v.x); o.y = f2bf(v.y); o.z = f2bf(v.z); o.w = f2bf(v.w);
    reinterpret_cast<ushort4*>(out)[((size_t)m * B_N + i) * 64 + d4] = o;
    float nx = bf2f(o.x), ny = bf2f(o.y), nz = bf2f(o.z), nw = bf2f(o.w);
    float s = nx * nx + ny * ny + nz * nz + nw * nw;
#pragma unroll
    for (int msk = 1; msk < 64; msk <<= 1) s += __shfl_xor(s, msk);
    if ((threadIdx.x & 63) == 0) norm2[m * B_N + i] = s;  // wave spans one (i,m) row
}

// Symmetric-pair main, no atomics, 512 threads = 8 waves x 32 rows.
// Identical to round 17 except __launch_bounds__(512) -- no min-waves arg,
// so the register allocator is NOT capped at 64 VGPR (r17's spill poison).
// Block = panel pair (a<=b), panels of 256 rows; 16 phases x 16 cols, dbuf
// LDS + verified XOR swizzle; row-side -> slot b, col-side (a<b) -> slot a;
// partials [slot][m][row] bf16 pairs (contiguous 1KB flushes).
// grid = 3m x 136 pairs = 408 blocks (~12.8 waves/CU).
__global__ __launch_bounds__(512) void main_kernel(
    const unsigned short* __restrict__ tokb, const int* __restrict__ labels,
    ushort2* __restrict__ partials) {
    int raw = blockIdx.x;
    int bid = (raw & 7) * 51 + (raw >> 3);   // bijective XCD swizzle (408 = 8*51)
    int m    = bid / 136;
    int beta = bid - m * 136;
    int b = 0;                                // triangular decode
    while ((b + 1) * (b + 2) / 2 <= beta) ++b;
    int a = beta - (b * (b + 1)) / 2;         // 0 <= a <= b <= 15
    bool offd = (a != b);
    int cb = b * 256;

    int tid  = threadIdx.x;
    int wave = tid >> 6, lane = tid & 63;
    int lr = lane & 15, lk = lane >> 4;
    const unsigned short* tm = tokb + (size_t)m * (B_N * D_N);

    __shared__ __align__(16) char ldsB[2][8192];
    __shared__ int labl[256];
    __shared__ float colbuf[8][16][16][2];
    if (tid < 256) labl[tid] = labels[cb + tid];

    // A fragments: rows r0 + rt*16 + lr (panel a), registers for whole kernel
    int r0 = a * 256 + wave * 32;
    bf16x8 afrag[2][8];
#pragma unroll
    for (int rt = 0; rt < 2; ++rt) {
        const unsigned short* rp = tm + (size_t)(r0 + rt * 16 + lr) * D_N + lk * 8;
#pragma unroll
        for (int kf = 0; kf < 8; ++kf)
            afrag[rt][kf] = *reinterpret_cast<const bf16x8*>(rp + kf * 32);
    }
    int labr[2][4];
#pragma unroll
    for (int rt = 0; rt < 2; ++rt)
#pragma unroll
        for (int j = 0; j < 4; ++j)
            labr[rt][j] = labels[r0 + rt * 16 + lk * 4 + j];

    float S[2][4] = {{0.f, 0.f, 0.f, 0.f}, {0.f, 0.f, 0.f, 0.f}};
    float P[2][4] = {{0.f, 0.f, 0.f, 0.f}, {0.f, 0.f, 0.f, 0.f}};

    // Staging (involution verified r4-r17; cb%8==0): thread t stages ONE 16B
    // chunk: col lc = t>>5 (0..15), chunk ch = t&31, source chunk ch^(lc&7),
    // LDS linear at t*16. Read applies the same XOR.
    int lc  = tid >> 5;
    int ch  = tid & 31;
    const unsigned short* sbase = tm + (size_t)(cb + lc) * D_N + (ch ^ (lc & 7)) * 8;

    // prologue: tile 0 -> buf0
    *reinterpret_cast<bf16x8*>(&ldsB[0][tid * 16]) = *reinterpret_cast<const bf16x8*>(sbase);

    for (int kb = 0; kb < 16; ++kb) {
        int cur = kb & 1;
        __syncthreads();   // buf[cur] staged; prior reads of buf[cur^1] drained

        int nkb = (kb + 1) & 15;   // wrap: last-iter load/write dead but safe
        bf16x8 nt = *reinterpret_cast<const bf16x8*>(sbase + (size_t)nkb * (16 * D_N));

        const char* bp = ldsB[cur];
        int swz = (lr & 7) << 4;
        bf16x8 bfrag[8];
#pragma unroll
        for (int kf = 0; kf < 8; ++kf)
            bfrag[kf] = *reinterpret_cast<const bf16x8*>(
                bp + lr * 512 + (((kf * 4 + lk) << 4) ^ swz));
        int labc = labl[kb * 16 + lr];

        f32x4 acc0 = {0.f, 0.f, 0.f, 0.f};
        f32x4 acc1 = {0.f, 0.f, 0.f, 0.f};
#pragma unroll
        for (int kf = 0; kf < 8; ++kf) {
            acc0 = __builtin_amdgcn_mfma_f32_16x16x32_bf16(afrag[0][kf], bfrag[kf], acc0, 0, 0, 0);
            acc1 = __builtin_amdgcn_mfma_f32_16x16x32_bf16(afrag[1][kf], bfrag[kf], acc1, 0, 0, 0);
        }

        float cs = 0.f, cp = 0.f;
        int cg0 = cb + kb * 16;
        if ((cg0 < r0 + 32) && (cg0 + 16 > r0)) {   // only in diag blocks
            int colg = cg0 + lr;
#pragma unroll
            for (int rt = 0; rt < 2; ++rt) {
                f32x4 aa = rt ? acc1 : acc0;
#pragma unroll
                for (int j = 0; j < 4; ++j) {
                    float s2 = aa[j];
                    float t = fminf(fmaf(s2, LOG2E, -C_OFF), T_CLAMP);
                    float e = __builtin_amdgcn_exp2f(t);
                    int row = r0 + rt * 16 + lk * 4 + j;
                    e = (colg == row) ? 0.f : e;    // exclude self from partition
                    bool mt = (labc == labr[rt][j]);
                    S[rt][j] += e;  P[rt][j] += mt ? s2 : 0.f;
                    cs += e;        cp += mt ? s2 : 0.f;
                }
            }
        } else {
#pragma unroll
            for (int rt = 0; rt < 2; ++rt) {
                f32x4 aa = rt ? acc1 : acc0;
#pragma unroll
                for (int j = 0; j < 4; ++j) {
                    float s2 = aa[j];
                    float t = fminf(fmaf(s2, LOG2E, -C_OFF), T_CLAMP);
                    float e = __builtin_amdgcn_exp2f(t);
                    bool mt = (labc == labr[rt][j]);
                    S[rt][j] += e;  P[rt][j] += mt ? s2 : 0.f;
                    cs += e;        cp += mt ? s2 : 0.f;
                }
            }
        }

        // col-side: sum over the wave's 32 rows (lanes lr, lr+16, lr+32, lr+48)
        cs += __shfl_xor(cs, 16); cs += __shfl_xor(cs, 32);
        cp += __shfl_xor(cp, 16); cp += __shfl_xor(cp, 32);
        if (lk == 0) { colbuf[wave][kb][lr][0] = cs; colbuf[wave][kb][lr][1] = cp; }

        // write next tile (other buffer); barrier at loop top publishes it
        *reinterpret_cast<bf16x8*>(&ldsB[cur ^ 1][tid * 16]) = nt;
    }

    __syncthreads();   // colbuf complete

    // row-side flush: reduce over 16 col-lanes, contiguous store to slot b
#pragma unroll
    for (int rt = 0; rt < 2; ++rt)
#pragma unroll
        for (int j = 0; j < 4; ++j) {
            float sv = S[rt][j], pv = P[rt][j];
#pragma unroll
            for (int msk = 1; msk < 16; msk <<= 1) {
                sv += __shfl_xor(sv, msk);
                pv += __shfl_xor(pv, msk);
            }
            if (lr == 0) {
                int row = r0 + rt * 16 + lk * 4 + j;
                ushort2 q; q.x = f2bf(sv); q.y = f2bf(pv);
                partials[(size_t)(b * 3 + m) * B_N + row] = q;
            }
        }

    // col-side flush (off-diag only): sum colbuf over 8 waves, store to slot a
    if (offd && tid < 256) {
        int kb = tid >> 4, cr = tid & 15;
        float sv = 0.f, pv = 0.f;
#pragma unroll
        for (int wv = 0; wv < 8; ++wv) {
            sv += colbuf[wv][kb][cr][0];
            pv += colbuf[wv][kb][cr][1];
        }
        int col = cb + tid;   // tid == kb*16 + cr
        ushort2 q; q.x = f2bf(sv); q.y = f2bf(pv);
        partials[(size_t)(a * 3 + m) * B_N + col] = q;
    }
}

// one thread per (m,i): merge 16 bf16 slot-partials, finish the loss term.
__global__ void reduce_kernel(const ushort2* __restrict__ partials,
                              const float* __restrict__ norm2,
                              const int* __restrict__ labels,
                              float* __restrict__ blockpart,
                              int* __restrict__ nvout) {
    __shared__ int h[32];
    int tid = threadIdx.x;
    if (tid < 32) h[tid] = 0;
    __syncthreads();
    for (int i = tid; i < B_N; i += 256) atomicAdd(&h[labels[i]], 1);
    __syncthreads();
    if (blockIdx.x == 0 && tid == 0) {
        int nv = 0;
#pragma unroll
        for (int c = 0; c < 32; ++c) nv += (h[c] >= 2) ? h[c] : 0;
        nvout[0] = nv;
    }
    int gid = blockIdx.x * 256 + tid;   // 12288 = m*4096 + i
    int m = gid >> 12, i = gid & 4095;
    float S = 0.f, P = 0.f;
#pragma unroll
    for (int s = 0; s < 16; ++s) {
        ushort2 q = partials[(size_t)(s * 3 + m) * B_N + i];
        S += bf2f(q.x); P += bf2f(q.y);
    }
    P -= norm2[gid];                       // remove self-sim from positive sum
    int pc = h[labels[i]] - 1;
    float contrib = (pc > 0)
        ? (__builtin_amdgcn_logf(S) + C_OFF) * LN2 - P / (float)pc
        : 0.f;
#pragma unroll
    for (int off = 32; off >= 1; off >>= 1) contrib += __shfl_down(contrib, off);
    __shared__ float w4[4];
    if ((tid & 63) == 0) w4[tid >> 6] = contrib;
    __syncthreads();
    if (tid == 0) blockpart[blockIdx.x] = w4[0] + w4[1] + w4[2] + w4[3];
}

__global__ void final_kernel(const float* __restrict__ blockpart, const int* __restrict__ nv,
                             float* __restrict__ out) {
    int lane = threadIdx.x;
    float s = (lane < 48) ? blockpart[lane] : 0.f;
#pragma unroll
    for (int off = 32; off >= 1; off >>= 1) s += __shfl_down(s, off);
    if (lane == 0) out[0] = s / (float)(nv[0] * M_N);
}

extern "C" void kernel_launch(void* const* d_in, const int* in_sizes, int n_in,
                              void* d_out, int out_size, void* d_ws, size_t ws_size,
                              hipStream_t stream) {
    const float* tokens = (const float*)d_in[0];
    const int*   labels = (const int*)d_in[1];
    float* out = (float*)d_out;

    char* ws = (char*)d_ws;
    int*     nv        = (int*)(ws + 128);                  // 1 int
    float*   blockpart = (float*)(ws + 256);                // 48 floats
    float*   norm2     = (float*)(ws + 1024);               // 12288 f32, ends 50176
    ushort2* partials  = (ushort2*)(ws + 65536);            // 16*3*4096*4B = 786432 B
    unsigned short* tokb = (unsigned short*)(ws + 1048576); // 6.29 MB (ends 7.34 MB)

    cvt_kernel<<<3072, 256, 0, stream>>>(tokens, tokb, norm2);
    main_kernel<<<408, 512, 0, stream>>>(tokb, labels, partials);
    reduce_kernel<<<48, 256, 0, stream>>>(partials, norm2, labels, blockpart, nv);
    final_kernel<<<1, 64, 0, stream>>>(blockpart, nv, out);
}

// Round 19
// 51.126 us; speedup vs baseline: 1.9205x; 1.0359x over previous
//
#include <hip/hip_runtime.h>

#define B_N 4096
#define M_N 3
#define D_N 256
#define LOG2E 1.44269504088896340736f
#define LN2   0.69314718055994530942f
#define C_OFF   64.0f
#define T_CLAMP 112.0f

typedef __bf16 bf16x8 __attribute__((ext_vector_type(8)));
typedef float  f32x4  __attribute__((ext_vector_type(4)));

__device__ __forceinline__ unsigned short f2bf(float f) {
    unsigned int u = __float_as_uint(f);
    u += 0x7FFFu + ((u >> 16) & 1u);   // round-to-nearest-even
    return (unsigned short)(u >> 16);
}
__device__ __forceinline__ float bf2f(unsigned short h) {
    return __uint_as_float(((unsigned int)h) << 16);
}

// tokens [i][m][d] f32 -> tokb [m][i][d] bf16; norm2[m*B+i] = sum(bf16(x)^2)
__global__ void cvt_kernel(const float* __restrict__ in, unsigned short* __restrict__ out,
                           float* __restrict__ norm2) {
    int idx = blockIdx.x * blockDim.x + threadIdx.x;   // 786432 float4s
    float4 v = reinterpret_cast<const float4*>(in)[idx];
    int i   = idx / 192;            // 192 = M*D/4
    int rem = idx - i * 192;
    int m   = rem >> 6;
    int d4  = rem & 63;
    ushort4 o;
    o.x = f2bf(v.x); o.y = f2bf(v.y); o.z = f2bf(v.z); o.w = f2bf(v.w);
    reinterpret_cast<ushort4*>(out)[((size_t)m * B_N + i) * 64 + d4] = o;
    float nx = bf2f(o.x), ny = bf2f(o.y), nz = bf2f(o.z), nw = bf2f(o.w);
    float s = nx * nx + ny * ny + nz * nz + nw * nw;
#pragma unroll
    for (int msk = 1; msk < 64; msk <<= 1) s += __shfl_xor(s, msk);
    if ((threadIdx.x & 63) == 0) norm2[m * B_N + i] = s;  // wave spans one (i,m) row
}

// Symmetric-pair main, no atomics. Panels of 128 rows -> 528 pairs (a<=b).
// Block = one pair: tile X_a.X_b^T (128x128, K=256), 8 phases x 16 cols,
// dbuf LDS + verified XOR swizzle, 4 waves x 32 rows -- per-phase code is the
// r13-measured form + r18-proven col-side adds. Row-side -> slot b, col-side
// (a<b) -> slot a; 32 slots, bijective, plain f32 stores (ws is 256 MB).
// grid = 3m x 528 = 1584 blocks (6.2/CU, ~4 co-resident -> raggedness amortized).
__global__ __launch_bounds__(256, 3) void main_kernel(
    const unsigned short* __restrict__ tokb, const int* __restrict__ labels,
    float2* __restrict__ partials) {
    int raw = blockIdx.x;
    int bid = (raw & 7) * 198 + (raw >> 3);  // bijective XCD swizzle (1584 = 8*198)
    int m    = bid / 528;
    int beta = bid - m * 528;
    int b = 0;                                // triangular decode
    while ((b + 1) * (b + 2) / 2 <= beta) ++b;
    int a = beta - (b * (b + 1)) / 2;         // 0 <= a <= b <= 31
    bool offd = (a != b);
    int cb = b * 128;

    int tid  = threadIdx.x;
    int wave = tid >> 6, lane = tid & 63;
    int lr = lane & 15, lk = lane >> 4;
    const unsigned short* tm = tokb + (size_t)m * (B_N * D_N);

    __shared__ __align__(16) char ldsB[2][8192];
    __shared__ int labl[128];
    __shared__ float colbuf[4][8][16][2];
    if (tid < 128) labl[tid] = labels[cb + tid];

    // A fragments: rows r0 + rt*16 + lr (panel a), registers for whole kernel
    int r0 = a * 128 + wave * 32;
    bf16x8 afrag[2][8];
#pragma unroll
    for (int rt = 0; rt < 2; ++rt) {
        const unsigned short* rp = tm + (size_t)(r0 + rt * 16 + lr) * D_N + lk * 8;
#pragma unroll
        for (int kf = 0; kf < 8; ++kf)
            afrag[rt][kf] = *reinterpret_cast<const bf16x8*>(rp + kf * 32);
    }
    int labr[2][4];
#pragma unroll
    for (int rt = 0; rt < 2; ++rt)
#pragma unroll
        for (int j = 0; j < 4; ++j)
            labr[rt][j] = labels[r0 + rt * 16 + lk * 4 + j];

    float S[2][4] = {{0.f, 0.f, 0.f, 0.f}, {0.f, 0.f, 0.f, 0.f}};
    float P[2][4] = {{0.f, 0.f, 0.f, 0.f}, {0.f, 0.f, 0.f, 0.f}};

    // Staging map (involution verified r4-r18; cb%8==0): thread (lc=tid>>5,
    // w=tid&31) loads source chunk w^(lc&7) of cols (cb+lc),(cb+lc+8); writes
    // LDS linearly at tid*16 / 4096+tid*16. Reads apply the same XOR.
    int lc  = tid >> 5;
    int w   = tid & 31;
    int sch = w ^ (lc & 7);
    const unsigned short* sbase = tm + (size_t)(cb + lc) * D_N + sch * 8;

    // prologue: tile 0 -> buf0
    {
        bf16x8 t0 = *reinterpret_cast<const bf16x8*>(sbase);
        bf16x8 t1 = *reinterpret_cast<const bf16x8*>(sbase + 8 * D_N);
        *reinterpret_cast<bf16x8*>(&ldsB[0][tid * 16])        = t0;
        *reinterpret_cast<bf16x8*>(&ldsB[0][4096 + tid * 16]) = t1;
    }

    for (int kb = 0; kb < 8; ++kb) {
        int cur = kb & 1;
        __syncthreads();   // buf[cur] staged; prior reads of buf[cur^1] drained

        int nkb = (kb + 1) & 7;    // wrap: last-iter load/write dead but safe
        const unsigned short* np = sbase + (size_t)nkb * (16 * D_N);
        bf16x8 nt0 = *reinterpret_cast<const bf16x8*>(np);
        bf16x8 nt1 = *reinterpret_cast<const bf16x8*>(np + 8 * D_N);

        const char* bp = ldsB[cur];
        int swz = (lr & 7) << 4;
        bf16x8 bfrag[8];
#pragma unroll
        for (int kf = 0; kf < 8; ++kf)
            bfrag[kf] = *reinterpret_cast<const bf16x8*>(
                bp + lr * 512 + (((kf * 4 + lk) << 4) ^ swz));
        int labc = labl[kb * 16 + lr];

        f32x4 acc0 = {0.f, 0.f, 0.f, 0.f};
        f32x4 acc1 = {0.f, 0.f, 0.f, 0.f};
#pragma unroll
        for (int kf = 0; kf < 8; ++kf) {
            acc0 = __builtin_amdgcn_mfma_f32_16x16x32_bf16(afrag[0][kf], bfrag[kf], acc0, 0, 0, 0);
            acc1 = __builtin_amdgcn_mfma_f32_16x16x32_bf16(afrag[1][kf], bfrag[kf], acc1, 0, 0, 0);
        }

        float cs = 0.f, cp = 0.f;
        int cg0 = cb + kb * 16;
        if ((cg0 < r0 + 32) && (cg0 + 16 > r0)) {   // only in diag blocks (a==b)
            int colg = cg0 + lr;
#pragma unroll
            for (int rt = 0; rt < 2; ++rt) {
                f32x4 aa = rt ? acc1 : acc0;
#pragma unroll
                for (int j = 0; j < 4; ++j) {
                    float s2 = aa[j];
                    float t = fminf(fmaf(s2, LOG2E, -C_OFF), T_CLAMP);
                    float e = __builtin_amdgcn_exp2f(t);
                    int row = r0 + rt * 16 + lk * 4 + j;
                    e = (colg == row) ? 0.f : e;    // exclude self from partition
                    bool mt = (labc == labr[rt][j]);
                    S[rt][j] += e;  P[rt][j] += mt ? s2 : 0.f;
                    cs += e;        cp += mt ? s2 : 0.f;
                }
            }
        } else {
#pragma unroll
            for (int rt = 0; rt < 2; ++rt) {
                f32x4 aa = rt ? acc1 : acc0;
#pragma unroll
                for (int j = 0; j < 4; ++j) {
                    float s2 = aa[j];
                    float t = fminf(fmaf(s2, LOG2E, -C_OFF), T_CLAMP);
                    float e = __builtin_amdgcn_exp2f(t);
                    bool mt = (labc == labr[rt][j]);
                    S[rt][j] += e;  P[rt][j] += mt ? s2 : 0.f;
                    cs += e;        cp += mt ? s2 : 0.f;
                }
            }
        }

        // col-side: sum over the wave's 32 rows (lanes lr, lr+16, lr+32, lr+48)
        cs += __shfl_xor(cs, 16); cs += __shfl_xor(cs, 32);
        cp += __shfl_xor(cp, 16); cp += __shfl_xor(cp, 32);
        if (lk == 0) { colbuf[wave][kb][lr][0] = cs; colbuf[wave][kb][lr][1] = cp; }

        // write next tile (other buffer); barrier at loop top publishes it
        char* dst = (char*)ldsB[cur ^ 1];
        *reinterpret_cast<bf16x8*>(dst + tid * 16)        = nt0;
        *reinterpret_cast<bf16x8*>(dst + 4096 + tid * 16) = nt1;
    }

    __syncthreads();   // colbuf complete

    // row-side flush: reduce over 16 col-lanes, store to slot b
#pragma unroll
    for (int rt = 0; rt < 2; ++rt)
#pragma unroll
        for (int j = 0; j < 4; ++j) {
            float sv = S[rt][j], pv = P[rt][j];
#pragma unroll
            for (int msk = 1; msk < 16; msk <<= 1) {
                sv += __shfl_xor(sv, msk);
                pv += __shfl_xor(pv, msk);
            }
            if (lr == 0) {
                int row = r0 + rt * 16 + lk * 4 + j;
                float2 q; q.x = sv; q.y = pv;
                partials[(size_t)(b * 3 + m) * B_N + row] = q;
            }
        }

    // col-side flush (off-diag only): sum colbuf over 4 waves, store to slot a
    if (offd && tid < 128) {
        int kb = tid >> 4, cr = tid & 15;
        float sv = colbuf[0][kb][cr][0] + colbuf[1][kb][cr][0]
                 + colbuf[2][kb][cr][0] + colbuf[3][kb][cr][0];
        float pv = colbuf[0][kb][cr][1] + colbuf[1][kb][cr][1]
                 + colbuf[2][kb][cr][1] + colbuf[3][kb][cr][1];
        int col = cb + tid;   // tid == kb*16 + cr
        float2 q; q.x = sv; q.y = pv;
        partials[(size_t)(a * 3 + m) * B_N + col] = q;
    }
}

// one thread per (m,i): merge 32 f32 slot-partials, finish the loss term.
__global__ void reduce_kernel(const float2* __restrict__ partials,
                              const float* __restrict__ norm2,
                              const int* __restrict__ labels,
                              float* __restrict__ blockpart,
                              int* __restrict__ nvout) {
    __shared__ int h[32];
    int tid = threadIdx.x;
    if (tid < 32) h[tid] = 0;
    __syncthreads();
    for (int i = tid; i < B_N; i += 256) atomicAdd(&h[labels[i]], 1);
    __syncthreads();
    if (blockIdx.x == 0 && tid == 0) {
        int nv = 0;
#pragma unroll
        for (int c = 0; c < 32; ++c) nv += (h[c] >= 2) ? h[c] : 0;
        nvout[0] = nv;
    }
    int gid = blockIdx.x * 256 + tid;   // 12288 = m*4096 + i
    int m = gid >> 12, i = gid & 4095;
    float S = 0.f, P = 0.f;
#pragma unroll
    for (int s = 0; s < 32; ++s) {
        float2 q = partials[(size_t)(s * 3 + m) * B_N + i];
        S += q.x; P += q.y;
    }
    P -= norm2[gid];                       // remove self-sim from positive sum
    int pc = h[labels[i]] - 1;
    float contrib = (pc > 0)
        ? (__builtin_amdgcn_logf(S) + C_OFF) * LN2 - P / (float)pc
        : 0.f;
#pragma unroll
    for (int off = 32; off >= 1; off >>= 1) contrib += __shfl_down(contrib, off);
    __shared__ float w4[4];
    if ((tid & 63) == 0) w4[tid >> 6] = contrib;
    __syncthreads();
    if (tid == 0) blockpart[blockIdx.x] = w4[0] + w4[1] + w4[2] + w4[3];
}

__global__ void final_kernel(const float* __restrict__ blockpart, const int* __restrict__ nv,
                             float* __restrict__ out) {
    int lane = threadIdx.x;
    float s = (lane < 48) ? blockpart[lane] : 0.f;
#pragma unroll
    for (int off = 32; off >= 1; off >>= 1) s += __shfl_down(s, off);
    if (lane == 0) out[0] = s / (float)(nv[0] * M_N);
}

extern "C" void kernel_launch(void* const* d_in, const int* in_sizes, int n_in,
                              void* d_out, int out_size, void* d_ws, size_t ws_size,
                              hipStream_t stream) {
    const float* tokens = (const float*)d_in[0];
    const int*   labels = (const int*)d_in[1];
    float* out = (float*)d_out;

    char* ws = (char*)d_ws;
    int*    nv        = (int*)(ws + 128);                   // 1 int
    float*  blockpart = (float*)(ws + 256);                 // 48 floats
    float*  norm2     = (float*)(ws + 1024);                // 12288 f32, ends 50176
    float2* partials  = (float2*)(ws + 65536);              // 32*3*4096*8B = 3.15 MB
    unsigned short* tokb = (unsigned short*)(ws + 3407872); // 6.29 MB, ends 9.7 MB
    // (ws is ~256 MB per harness poison-fill evidence; 9.7 MB is comfortably inside)

    cvt_kernel<<<3072, 256, 0, stream>>>(tokens, tokb, norm2);
    main_kernel<<<1584, 256, 0, stream>>>(tokb, labels, partials);
    reduce_kernel<<<48, 256, 0, stream>>>(partials, norm2, labels, blockpart, nv);
    final_kernel<<<1, 64, 0, stream>>>(blockpart, nv, out);
}